// Round 6
// baseline (221.643 us; speedup 1.0000x reference)
//
#include <hip/hip_runtime.h>
#include <math.h>

#define NN 64      // nodes per graph
#define HH 128     // hidden channels
#define NBB 8      // bessel basis
#define TT 32      // time embedding dim
#define BB 64      // batch

typedef __attribute__((ext_vector_type(8))) short short8;
typedef __attribute__((ext_vector_type(4))) float f32x4;
typedef __attribute__((ext_vector_type(2))) float f32x2;

__device__ __forceinline__ float silu_f(float x) {
  return x * __builtin_amdgcn_rcpf(1.0f + __expf(-x));
}

__device__ __forceinline__ unsigned short f2bf(float x) {
  union { float f; unsigned u; } v; v.f = x;
  unsigned r = v.u + 0x7FFFu + ((v.u >> 16) & 1u);   // round-to-nearest-even
  return (unsigned short)(r >> 16);
}

// One block per graph b: pack a 512-elem slice of Wr2 -> bf16 B-frag order,
// compute h[b,n,:] = emb[z[b,n],:] + gf[b,:] @ Wt.
__global__ __launch_bounds__(256) void k_init(
    const float* __restrict__ emb, const int* __restrict__ z,
    const float* __restrict__ gf, const float* __restrict__ Wt,
    const float* __restrict__ Wr2, float* __restrict__ h,
    unsigned short* __restrict__ Wr2p) {
  __shared__ float tvec[HH];
  __shared__ int sz[NN];
  int b = blockIdx.x, tid = threadIdx.x;
#pragma unroll
  for (int ii = 0; ii < 2; ++ii) {        // Wr2 pack: dst[(((l*4+kt)*128+n)*4+q)*8+j]
    int idx = b * 512 + ii * 256 + tid;
    int l = idx >> 14, k = (idx >> 7) & 127, n = idx & 127;
    int kt = k >> 5, q = (k >> 3) & 3, j = k & 7;
    Wr2p[((((l * 4 + kt) * 128 + n) * 4 + q) * 8) + j] = f2bf(Wr2[idx]);
  }
  if (tid < NN) sz[tid] = z[b * NN + tid];
  if (tid < HH) {
    float acc = 0.f;
#pragma unroll
    for (int k = 0; k < TT; ++k) acc += gf[b * TT + k] * Wt[k * HH + tid];
    tvec[tid] = acc;
  }
  __syncthreads();
  for (int i = tid; i < NN * HH; i += 256) {
    int n = i >> 7, c = i & 127;
    h[(size_t)b * NN * HH + i] = emb[sz[n] * HH + c] + tvec[c];
  }
}

// One block (256 thr = 4 waves) per (b, receiver r).
// A: rb/u (flat over 256 threads, transposed LDS layout -> conflict-free).
// B: S = silu(rb@Wr1) -> bf16 LDS. GEMM: w = S@Wr2 via mfma.
// Epilogue: m0 = w*h[snd], weight by u, quad-reduce, write a0a1[blk][c][4].
__global__ __launch_bounds__(256) void k_layer(
    const float* __restrict__ pos,
    const float* __restrict__ hin,
    float* __restrict__ a0a1,
    const float* __restrict__ Wr1, const unsigned short* __restrict__ Wr2p,
    int l) {
  __shared__ __align__(16) unsigned short sh_S[NN][136];   // +8 pad: conflict-free frags
  __shared__ __align__(16) float sh_rb[NBB][NN];           // k-major: stride-4B writes
  __shared__ __align__(16) float sh_u[3][NN];

  int blk = blockIdx.x;          // b*NN + r
  int b = blk >> 6, r = blk & 63;
  int tid = threadIdx.x;
  int w = tid >> 6, lane = tid & 63;

  // ---- Stage A: geometry + bessel, flat over all 256 threads ----
  {
    int s = tid & 63, ksel = tid >> 6;    // each thread: one sender, two basis terms
    const float* pb = pos + b * NN * 3;
    float dx = pb[r * 3 + 0] - pb[s * 3 + 0];
    float dy = pb[r * 3 + 1] - pb[s * 3 + 1];
    float dz = pb[r * 3 + 2] - pb[s * 3 + 2];
    float rr = sqrtf(dx * dx + dy * dy + dz * dz + 1e-12f);
    float inv = __builtin_amdgcn_rcpf(rr);
    if (ksel == 0) {
      sh_u[0][s] = dx * inv; sh_u[1][s] = dy * inv; sh_u[2][s] = dz * inv;
    }
    const float PI_OVER_5 = 0.628318530717958647692f;
    float fc = (s != r && rr < 5.0f) ? 0.5f * (__cosf(PI_OVER_5 * rr) + 1.0f) : 0.0f;
    float base = PI_OVER_5 * rr;
    float sc = inv * fc;
    sh_rb[ksel * 2 + 0][s] = __sinf((float)(ksel * 2 + 1) * base) * sc;
    sh_rb[ksel * 2 + 1][s] = __sinf((float)(ksel * 2 + 2) * base) * sc;
  }
  __syncthreads();

  // ---- Stage B: S[s][c] = silu(rb[s]@Wr1[:,c]) -> bf16; wave w: s in [w*16, w*16+16) ----
  {
    const float* Wr1l = Wr1 + l * NBB * HH;
    int c0 = 2 * lane;
    float wc0[NBB], wc1[NBB];
#pragma unroll
    for (int k = 0; k < NBB; ++k) { wc0[k] = Wr1l[k * HH + c0]; wc1[k] = Wr1l[k * HH + c0 + 1]; }
    int sbase = w * 16;
#pragma unroll 4
    for (int si = 0; si < 16; ++si) {
      int s = sbase + si;
      float rbv[NBB];
#pragma unroll
      for (int k = 0; k < NBB; ++k) rbv[k] = sh_rb[k][s];   // LDS broadcast (free)
      float a0 = 0.f, a1 = 0.f;
#pragma unroll
      for (int k = 0; k < NBB; ++k) { a0 += rbv[k] * wc0[k]; a1 += rbv[k] * wc1[k]; }
      unsigned packed = (unsigned)f2bf(silu_f(a0)) | ((unsigned)f2bf(silu_f(a1)) << 16);
      *(unsigned*)&sh_S[s][c0] = packed;
    }
  }
  __syncthreads();

  // ---- GEMM + message epilogue (wave w owns c in [w*32, w*32+32)) ----
  const unsigned short* Bbase = Wr2p + l * 16384;
  int nlo = lane & 15, quad = lane >> 4;
  short8 bfr[4][2];
#pragma unroll
  for (int kt = 0; kt < 4; ++kt)
#pragma unroll
    for (int nt = 0; nt < 2; ++nt) {
      int c = w * 32 + nt * 16 + nlo;
      bfr[kt][nt] = *(const short8*)&Bbase[((kt * 128 + c) * 4 + quad) * 8];
    }
  float acc0[2] = {0.f, 0.f};
  float a1x[2] = {0.f, 0.f};
  float a1y[2] = {0.f, 0.f};
  float a1z[2] = {0.f, 0.f};
  const float* hb = hin + (size_t)b * NN * HH;

#pragma unroll
  for (int mt = 0; mt < 4; ++mt) {
    short8 afr[4];
    int s_a = mt * 16 + nlo;
#pragma unroll
    for (int kt = 0; kt < 4; ++kt)
      afr[kt] = *(const short8*)&sh_S[s_a][kt * 32 + quad * 8];
    float ux[4], uy[4], uz[4];
#pragma unroll
    for (int reg = 0; reg < 4; ++reg) {
      int s = mt * 16 + quad * 4 + reg;
      ux[reg] = sh_u[0][s]; uy[reg] = sh_u[1][s]; uz[reg] = sh_u[2][s];
    }
#pragma unroll
    for (int nt = 0; nt < 2; ++nt) {
      int c = w * 32 + nt * 16 + nlo;
      f32x4 C = {0.f, 0.f, 0.f, 0.f};
#pragma unroll
      for (int kt = 0; kt < 4; ++kt)
        C = __builtin_amdgcn_mfma_f32_16x16x32_bf16(afr[kt], bfr[kt][nt], C, 0, 0, 0);
#pragma unroll
      for (int reg = 0; reg < 4; ++reg) {
        int s = mt * 16 + quad * 4 + reg;
        float m0 = C[reg] * hb[s * HH + c];
        acc0[nt] += m0;
        a1x[nt] += m0 * ux[reg];
        a1y[nt] += m0 * uy[reg];
        a1z[nt] += m0 * uz[reg];
      }
    }
  }

  // quad-reduce -> global a0a1[blk][c][{a0,a1x,a1y,a1z}]
  const float invAvg = 1.0f / 63.0f;
#pragma unroll
  for (int nt = 0; nt < 2; ++nt) {
    float q0 = acc0[nt], q1 = a1x[nt], q2 = a1y[nt], q3 = a1z[nt];
    q0 += __shfl_xor(q0, 16); q0 += __shfl_xor(q0, 32);
    q1 += __shfl_xor(q1, 16); q1 += __shfl_xor(q1, 32);
    q2 += __shfl_xor(q2, 16); q2 += __shfl_xor(q2, 32);
    q3 += __shfl_xor(q3, 16); q3 += __shfl_xor(q3, 32);
    if (quad == 0) {
      int c = w * 32 + nt * 16 + nlo;
      f32x4 val = {q0 * invAvg, q1 * invAvg, q2 * invAvg, q3 * invAvg};
      *(f32x4*)&a0a1[((size_t)blk * HH + c) * 4] = val;
    }
  }
}

// Batched node update, 4 rows/block (grid 1024): hout = hin + a0@Wul ; v = a1@Wml.
__global__ __launch_bounds__(256) void k_update(
    const float* __restrict__ a0a1, const float* __restrict__ hin,
    float* __restrict__ hout, float* __restrict__ v,
    const float* __restrict__ Wul, const float* __restrict__ Wml) {
  __shared__ __align__(16) f32x4 sh_a[4][HH];     // 8 KB
  int tid = threadIdx.x;
  int row0 = blockIdx.x * 4;
  const f32x4* src = (const f32x4*)(a0a1 + (size_t)row0 * HH * 4);
  for (int i = tid; i < 4 * HH; i += 256) sh_a[i >> 7][i & 127] = src[i];
  __syncthreads();
  int c2 = (tid & 63) * 2;
  int rr = tid >> 6;                      // one row per wave
  f32x2 hA = {0, 0}, xA = {0, 0}, yA = {0, 0}, zA = {0, 0};
#pragma unroll 4
  for (int g = 0; g < HH; ++g) {
    f32x2 wu = *(const f32x2*)&Wul[g * HH + c2];
    f32x2 wm = *(const f32x2*)&Wml[g * HH + c2];
    f32x4 a = sh_a[rr][g];                // wave-broadcast
    hA += a.x * wu; xA += a.y * wm; yA += a.z * wm; zA += a.w * wm;
  }
  size_t rA = row0 + rr;
  f32x2 t = *(const f32x2*)&hin[rA * HH + c2]; t += hA;
  *(f32x2*)&hout[rA * HH + c2] = t;
  *(f32x2*)&v[(rA * 3 + 0) * HH + c2] = xA;
  *(f32x2*)&v[(rA * 3 + 1) * HH + c2] = yA;
  *(f32x2*)&v[(rA * 3 + 2) * HH + c2] = zA;
}

// Layer-1 update fused with readout, 4 rows/block (grid 1024):
// h/v rows in LDS; g = silu(h@Wg1)@Wg2; out[n,d] = sum_c v[n,c,d]*g[n,c] * fs.
__global__ __launch_bounds__(256) void k_update_ro(
    const float* __restrict__ a0a1, const float* __restrict__ hin,
    const float* __restrict__ v,
    const float* __restrict__ Wul, const float* __restrict__ Wml,
    const float* __restrict__ Wg1, const float* __restrict__ Wg2,
    const float* __restrict__ fs, float* __restrict__ out) {
  __shared__ __align__(16) f32x4 sh_a[4][HH];     // 8 KB (aliased by q/g later)
  __shared__ float sh_h[4][HH];                   // 2 KB
  __shared__ float sh_v[4][3][132];               // 6.3 KB (+4 pad)
  float* sh_q = (float*)&sh_a[0][0];              // 2 KB (aliases dead sh_a)
  float* sh_g = (float*)&sh_a[2][0];              // 2 KB
  int tid = threadIdx.x;
  int row0 = blockIdx.x * 4;
  const f32x4* src = (const f32x4*)(a0a1 + (size_t)row0 * HH * 4);
  for (int i = tid; i < 4 * HH; i += 256) sh_a[i >> 7][i & 127] = src[i];
  __syncthreads();
  // ---- update phase: one row per wave ----
  {
    int c2 = (tid & 63) * 2;
    int rr = tid >> 6;
    f32x2 hA = {0, 0}, xA = {0, 0}, yA = {0, 0}, zA = {0, 0};
#pragma unroll 4
    for (int g = 0; g < HH; ++g) {
      f32x2 wu = *(const f32x2*)&Wul[g * HH + c2];
      f32x2 wm = *(const f32x2*)&Wml[g * HH + c2];
      f32x4 a = sh_a[rr][g];
      hA += a.x * wu; xA += a.y * wm; yA += a.z * wm; zA += a.w * wm;
    }
    size_t rA = row0 + rr;
    sh_h[rr][c2]     = hin[rA * HH + c2]     + hA.x;
    sh_h[rr][c2 + 1] = hin[rA * HH + c2 + 1] + hA.y;
    sh_v[rr][0][c2]     = v[(rA * 3 + 0) * HH + c2]     + xA.x;
    sh_v[rr][0][c2 + 1] = v[(rA * 3 + 0) * HH + c2 + 1] + xA.y;
    sh_v[rr][1][c2]     = v[(rA * 3 + 1) * HH + c2]     + yA.x;
    sh_v[rr][1][c2 + 1] = v[(rA * 3 + 1) * HH + c2 + 1] + yA.y;
    sh_v[rr][2][c2]     = v[(rA * 3 + 2) * HH + c2]     + zA.x;
    sh_v[rr][2][c2 + 1] = v[(rA * 3 + 2) * HH + c2 + 1] + zA.y;
  }
  __syncthreads();
  // gate GEMM 1: q = silu(h @ Wg1); half-block handles 2 rows
  {
    int c = tid & 127, r2 = (tid >> 7) * 2;
    float q0 = 0.f, q1 = 0.f;
#pragma unroll 4
    for (int k = 0; k < HH; ++k) {
      float wg = Wg1[k * HH + c];
      q0 += sh_h[r2][k] * wg;
      q1 += sh_h[r2 + 1][k] * wg;
    }
    sh_q[r2 * HH + c] = silu_f(q0);
    sh_q[(r2 + 1) * HH + c] = silu_f(q1);
  }
  __syncthreads();
  // gate GEMM 2: g = q @ Wg2
  {
    int c = tid & 127, r2 = (tid >> 7) * 2;
    float g0 = 0.f, g1 = 0.f;
#pragma unroll 4
    for (int k = 0; k < HH; ++k) {
      float wg = Wg2[k * HH + c];
      g0 += sh_q[r2 * HH + k] * wg;
      g1 += sh_q[(r2 + 1) * HH + k] * wg;
    }
    sh_g[r2 * HH + c] = g0;
    sh_g[(r2 + 1) * HH + c] = g1;
  }
  __syncthreads();
  // contraction: out[row,d] = sum_c v[row][d][c]*g[row][c]; one row per wave
  {
    int row = tid >> 6, i = tid & 63;
    float px = 0.f, py = 0.f, pz = 0.f;
#pragma unroll
    for (int t = 0; t < 2; ++t) {
      int cc = i + t * 64;
      float gv = sh_g[row * HH + cc];
      px += sh_v[row][0][cc] * gv;
      py += sh_v[row][1][cc] * gv;
      pz += sh_v[row][2][cc] * gv;
    }
#pragma unroll
    for (int off = 32; off > 0; off >>= 1) {
      px += __shfl_down(px, off);
      py += __shfl_down(py, off);
      pz += __shfl_down(pz, off);
    }
    if (i == 0) {
      float s = fs[0];
      size_t o = ((size_t)(row0 + row)) * 3;
      out[o + 0] = px * s; out[o + 1] = py * s; out[o + 2] = pz * s;
    }
  }
}

extern "C" void kernel_launch(void* const* d_in, const int* in_sizes, int n_in,
                              void* d_out, int out_size, void* d_ws, size_t ws_size,
                              hipStream_t stream) {
  const float* pos  = (const float*)d_in[0];
  const int*   z    = (const int*)d_in[1];
  const float* gf   = (const float*)d_in[2];
  const float* emb  = (const float*)d_in[3];
  const float* Wt   = (const float*)d_in[4];
  const float* Wr1  = (const float*)d_in[5];
  const float* Wr2  = (const float*)d_in[6];
  const float* Wupd = (const float*)d_in[7];
  const float* Wmix = (const float*)d_in[8];
  const float* Wg1  = (const float*)d_in[9];
  const float* Wg2  = (const float*)d_in[10];
  const float* fs   = (const float*)d_in[11];
  float* out = (float*)d_out;

  float* ws = (float*)d_ws;
  const size_t HN = (size_t)BB * NN * HH;   // 524288
  float* hA   = ws;                          // 2 MB
  float* hB   = ws + HN;                     // 2 MB
  float* v    = ws + 2 * HN;                 // 6 MB
  float* a0a1 = ws + 5 * HN;                 // 8 MB ([4096][128][4])
  unsigned short* Wr2p = (unsigned short*)(ws + 9 * HN);  // 64 KB

  k_init<<<dim3(BB), dim3(256), 0, stream>>>(emb, z, gf, Wt, Wr2, hA, Wr2p);
  k_layer<<<dim3(BB * NN), dim3(256), 0, stream>>>(pos, hA, a0a1, Wr1, Wr2p, 0);
  k_update<<<dim3(1024), dim3(256), 0, stream>>>(a0a1, hA, hB, v, Wupd, Wmix);
  k_layer<<<dim3(BB * NN), dim3(256), 0, stream>>>(pos, hB, a0a1, Wr1, Wr2p, 1);
  k_update_ro<<<dim3(1024), dim3(256), 0, stream>>>(a0a1, hB, v,
      Wupd + 16384, Wmix + 16384, Wg1, Wg2, fs, out);
}

// Round 7
// 176.012 us; speedup vs baseline: 1.2593x; 1.2593x over previous
//
#include <hip/hip_runtime.h>
#include <math.h>

#define NN 64      // nodes per graph
#define HH 128     // hidden channels
#define NBB 8      // bessel basis
#define TT 32      // time embedding dim
#define BB 64      // batch
#define NROW (BB * NN)        // 4096 total rows
#define PLANE ((size_t)NROW * HH)   // 524288

typedef __attribute__((ext_vector_type(8))) short short8;
typedef __attribute__((ext_vector_type(4))) float f32x4;
typedef __attribute__((ext_vector_type(2))) float f32x2;

__device__ __forceinline__ float silu_f(float x) {
  return x * __builtin_amdgcn_rcpf(1.0f + __expf(-x));
}

__device__ __forceinline__ unsigned short f2bf(float x) {
  union { float f; unsigned u; } v; v.f = x;
  unsigned r = v.u + 0x7FFFu + ((v.u >> 16) & 1u);   // round-to-nearest-even
  return (unsigned short)(r >> 16);
}

// 32-row MFMA GEMM tile: C[2][2] += shA[32][128(136)] @ B (packed frag order).
// Wave w owns cols w*32..w*32+31. C mapping: row=mt*16+quad*4+reg, col=w*32+nt*16+nlo.
__device__ __forceinline__ void gemm32(
    const unsigned short (*sA)[136], const unsigned short* __restrict__ Bp,
    int w, int nlo, int quad, f32x4 C[2][2]) {
  short8 bfr[4][2];
#pragma unroll
  for (int kt = 0; kt < 4; ++kt)
#pragma unroll
    for (int nt = 0; nt < 2; ++nt)
      bfr[kt][nt] = *(const short8*)&Bp[((kt * 128 + w * 32 + nt * 16 + nlo) * 4 + quad) * 8];
#pragma unroll
  for (int mt = 0; mt < 2; ++mt) {
    short8 afr[4];
#pragma unroll
    for (int kt = 0; kt < 4; ++kt)
      afr[kt] = *(const short8*)&sA[mt * 16 + nlo][kt * 32 + quad * 8];
#pragma unroll
    for (int nt = 0; nt < 2; ++nt)
#pragma unroll
      for (int kt = 0; kt < 4; ++kt)
        C[mt][nt] = __builtin_amdgcn_mfma_f32_16x16x32_bf16(afr[kt], bfr[kt][nt], C[mt][nt], 0, 0, 0);
  }
}

// Grid 64. Pack all 8 weight matrices -> bf16 MFMA-B-frag order; init h.
// Pack order: [0,1]=Wr2 l0/l1, [2,3]=Wupd, [4,5]=Wmix, [6]=Wg1, [7]=Wg2.
__global__ __launch_bounds__(256) void k_init(
    const float* __restrict__ emb, const int* __restrict__ z,
    const float* __restrict__ gf, const float* __restrict__ Wt,
    const float* __restrict__ Wr2, const float* __restrict__ Wupd,
    const float* __restrict__ Wmix, const float* __restrict__ Wg1,
    const float* __restrict__ Wg2,
    float* __restrict__ h, unsigned short* __restrict__ Wpack) {
  __shared__ float tvec[HH];
  __shared__ int sz[NN];
  int b = blockIdx.x, tid = threadIdx.x;
#pragma unroll
  for (int ii = 0; ii < 8; ++ii) {
    int idx = b * 2048 + ii * 256 + tid;    // 0..131071
    int m = idx >> 14;
    int local = idx & 16383;
    float val;
    if (m < 2) val = Wr2[idx];
    else if (m < 4) val = Wupd[idx - 32768];
    else if (m < 6) val = Wmix[idx - 65536];
    else if (m == 6) val = Wg1[local];
    else val = Wg2[local];
    int k = local >> 7, n = local & 127;
    int kt = k >> 5, q = (k >> 3) & 3, j = k & 7;
    Wpack[(idx & ~16383) + (((kt * 128 + n) * 4 + q) * 8) + j] = f2bf(val);
  }
  if (tid < NN) sz[tid] = z[b * NN + tid];
  if (tid < HH) {
    float acc = 0.f;
#pragma unroll
    for (int k = 0; k < TT; ++k) acc += gf[b * TT + k] * Wt[k * HH + tid];
    tvec[tid] = acc;
  }
  __syncthreads();
  for (int i = tid; i < NN * HH; i += 256) {
    int n = i >> 7, c = i & 127;
    h[(size_t)b * NN * HH + i] = emb[sz[n] * HH + c] + tvec[c];
  }
}

// One block (256 thr = 4 waves) per (b, receiver r). Writes a-planes:
// ap[0]=a0, ap[1]=a1x, ap[2]=a1y, ap[3]=a1z, each [4096][128] fp32.
__global__ __launch_bounds__(256) void k_layer(
    const float* __restrict__ pos,
    const float* __restrict__ hin,
    float* __restrict__ ap,
    const float* __restrict__ Wr1, const unsigned short* __restrict__ Wpack,
    int l) {
  __shared__ __align__(16) unsigned short sh_S[NN][136];
  __shared__ __align__(16) float sh_rb[NBB][NN];
  __shared__ __align__(16) float sh_u[3][NN];

  int blk = blockIdx.x;          // b*NN + r
  int b = blk >> 6, r = blk & 63;
  int tid = threadIdx.x;
  int w = tid >> 6, lane = tid & 63;

  // ---- Stage A: geometry + bessel, flat over all 256 threads ----
  {
    int s = tid & 63, ksel = tid >> 6;
    const float* pb = pos + b * NN * 3;
    float dx = pb[r * 3 + 0] - pb[s * 3 + 0];
    float dy = pb[r * 3 + 1] - pb[s * 3 + 1];
    float dz = pb[r * 3 + 2] - pb[s * 3 + 2];
    float rr = sqrtf(dx * dx + dy * dy + dz * dz + 1e-12f);
    float inv = __builtin_amdgcn_rcpf(rr);
    if (ksel == 0) {
      sh_u[0][s] = dx * inv; sh_u[1][s] = dy * inv; sh_u[2][s] = dz * inv;
    }
    const float PI_OVER_5 = 0.628318530717958647692f;
    float fc = (s != r && rr < 5.0f) ? 0.5f * (__cosf(PI_OVER_5 * rr) + 1.0f) : 0.0f;
    float base = PI_OVER_5 * rr;
    float sc = inv * fc;
    sh_rb[ksel * 2 + 0][s] = __sinf((float)(ksel * 2 + 1) * base) * sc;
    sh_rb[ksel * 2 + 1][s] = __sinf((float)(ksel * 2 + 2) * base) * sc;
  }
  __syncthreads();

  // ---- Stage B: S = silu(rb@Wr1) -> bf16 ----
  {
    const float* Wr1l = Wr1 + l * NBB * HH;
    int c0 = 2 * lane;
    float wc0[NBB], wc1[NBB];
#pragma unroll
    for (int k = 0; k < NBB; ++k) { wc0[k] = Wr1l[k * HH + c0]; wc1[k] = Wr1l[k * HH + c0 + 1]; }
    int sbase = w * 16;
#pragma unroll 4
    for (int si = 0; si < 16; ++si) {
      int s = sbase + si;
      float rbv[NBB];
#pragma unroll
      for (int k = 0; k < NBB; ++k) rbv[k] = sh_rb[k][s];
      float a0 = 0.f, a1 = 0.f;
#pragma unroll
      for (int k = 0; k < NBB; ++k) { a0 += rbv[k] * wc0[k]; a1 += rbv[k] * wc1[k]; }
      unsigned packed = (unsigned)f2bf(silu_f(a0)) | ((unsigned)f2bf(silu_f(a1)) << 16);
      *(unsigned*)&sh_S[s][c0] = packed;
    }
  }
  __syncthreads();

  // ---- GEMM + message epilogue ----
  const unsigned short* Bbase = Wpack + l * 16384;
  int nlo = lane & 15, quad = lane >> 4;
  short8 bfr[4][2];
#pragma unroll
  for (int kt = 0; kt < 4; ++kt)
#pragma unroll
    for (int nt = 0; nt < 2; ++nt) {
      int c = w * 32 + nt * 16 + nlo;
      bfr[kt][nt] = *(const short8*)&Bbase[((kt * 128 + c) * 4 + quad) * 8];
    }
  float acc0[2] = {0.f, 0.f};
  float a1x[2] = {0.f, 0.f};
  float a1y[2] = {0.f, 0.f};
  float a1z[2] = {0.f, 0.f};
  const float* hb = hin + (size_t)b * NN * HH;

#pragma unroll
  for (int mt = 0; mt < 4; ++mt) {
    short8 afr[4];
    int s_a = mt * 16 + nlo;
#pragma unroll
    for (int kt = 0; kt < 4; ++kt)
      afr[kt] = *(const short8*)&sh_S[s_a][kt * 32 + quad * 8];
    float ux[4], uy[4], uz[4];
#pragma unroll
    for (int reg = 0; reg < 4; ++reg) {
      int s = mt * 16 + quad * 4 + reg;
      ux[reg] = sh_u[0][s]; uy[reg] = sh_u[1][s]; uz[reg] = sh_u[2][s];
    }
#pragma unroll
    for (int nt = 0; nt < 2; ++nt) {
      int c = w * 32 + nt * 16 + nlo;
      f32x4 C = {0.f, 0.f, 0.f, 0.f};
#pragma unroll
      for (int kt = 0; kt < 4; ++kt)
        C = __builtin_amdgcn_mfma_f32_16x16x32_bf16(afr[kt], bfr[kt][nt], C, 0, 0, 0);
#pragma unroll
      for (int reg = 0; reg < 4; ++reg) {
        int s = mt * 16 + quad * 4 + reg;
        float m0 = C[reg] * hb[s * HH + c];
        acc0[nt] += m0;
        a1x[nt] += m0 * ux[reg];
        a1y[nt] += m0 * uy[reg];
        a1z[nt] += m0 * uz[reg];
      }
    }
  }

  const float invAvg = 1.0f / 63.0f;
#pragma unroll
  for (int nt = 0; nt < 2; ++nt) {
    float q0 = acc0[nt], q1 = a1x[nt], q2 = a1y[nt], q3 = a1z[nt];
    q0 += __shfl_xor(q0, 16); q0 += __shfl_xor(q0, 32);
    q1 += __shfl_xor(q1, 16); q1 += __shfl_xor(q1, 32);
    q2 += __shfl_xor(q2, 16); q2 += __shfl_xor(q2, 32);
    q3 += __shfl_xor(q3, 16); q3 += __shfl_xor(q3, 32);
    if (quad == 0) {
      size_t base = (size_t)blk * HH + w * 32 + nt * 16 + nlo;
      ap[base]             = q0 * invAvg;
      ap[PLANE + base]     = q1 * invAvg;
      ap[2 * PLANE + base] = q2 * invAvg;
      ap[3 * PLANE + base] = q3 * invAvg;
    }
  }
}

// Layer-0 node update via MFMA, 32 rows/block (grid 128):
// hout = hin + a0@Wupd0 ; v planes = a1@Wmix0.
__global__ __launch_bounds__(256) void k_update(
    const float* __restrict__ ap, const float* __restrict__ hin,
    float* __restrict__ hout, float* __restrict__ vp,
    const unsigned short* __restrict__ Wpack) {
  __shared__ __align__(16) unsigned short sh_a[4][32][136];
  int tid = threadIdx.x, w = tid >> 6, lane = tid & 63;
  int nlo = lane & 15, quad = lane >> 4;
  int row0 = blockIdx.x * 32;
#pragma unroll
  for (int p = 0; p < 4; ++p)
    for (int i = tid; i < 32 * 64; i += 256) {
      int rr = i >> 6, c2 = (i & 63) * 2;
      f32x2 t = *(const f32x2*)&ap[p * PLANE + (size_t)(row0 + rr) * HH + c2];
      *(unsigned*)&sh_a[p][rr][c2] = (unsigned)f2bf(t.x) | ((unsigned)f2bf(t.y) << 16);
    }
  __syncthreads();
  f32x4 Ch[2][2], Cx[2][2], Cy[2][2], Cz[2][2];
#pragma unroll
  for (int mt = 0; mt < 2; ++mt)
#pragma unroll
    for (int nt = 0; nt < 2; ++nt) {
      Ch[mt][nt] = (f32x4){0,0,0,0}; Cx[mt][nt] = (f32x4){0,0,0,0};
      Cy[mt][nt] = (f32x4){0,0,0,0}; Cz[mt][nt] = (f32x4){0,0,0,0};
    }
  gemm32(sh_a[0], Wpack + 2 * 16384, w, nlo, quad, Ch);
  gemm32(sh_a[1], Wpack + 4 * 16384, w, nlo, quad, Cx);
  gemm32(sh_a[2], Wpack + 4 * 16384, w, nlo, quad, Cy);
  gemm32(sh_a[3], Wpack + 4 * 16384, w, nlo, quad, Cz);
#pragma unroll
  for (int mt = 0; mt < 2; ++mt)
#pragma unroll
    for (int nt = 0; nt < 2; ++nt)
#pragma unroll
      for (int reg = 0; reg < 4; ++reg) {
        size_t row = row0 + mt * 16 + quad * 4 + reg;
        int col = w * 32 + nt * 16 + nlo;
        hout[row * HH + col] = hin[row * HH + col] + Ch[mt][nt][reg];
        vp[0 * PLANE + row * HH + col] = Cx[mt][nt][reg];
        vp[1 * PLANE + row * HH + col] = Cy[mt][nt][reg];
        vp[2 * PLANE + row * HH + col] = Cz[mt][nt][reg];
      }
}

// Layer-1 update + full readout, 32 rows/block (grid 128), 7 MFMA GEMMs in-block:
// h = hin + a0@Wupd1; v = vin + a1@Wmix1; g = silu(h@Wg1)@Wg2;
// out[row,d] = sum_c v[row,c,d]*g[row,c] * fs.
__global__ __launch_bounds__(256) void k_update_ro(
    const float* __restrict__ ap, const float* __restrict__ hin,
    const float* __restrict__ vp,
    const unsigned short* __restrict__ Wpack,
    const float* __restrict__ fs, float* __restrict__ out) {
  __shared__ __align__(16) unsigned short sh_a[4][32][136];   // a-tiles; [0] aliased by q
  __shared__ __align__(16) unsigned short sh_h[32][136];
  __shared__ float red[4][32][3];
  int tid = threadIdx.x, w = tid >> 6, lane = tid & 63;
  int nlo = lane & 15, quad = lane >> 4;
  int row0 = blockIdx.x * 32;
#pragma unroll
  for (int p = 0; p < 4; ++p)
    for (int i = tid; i < 32 * 64; i += 256) {
      int rr = i >> 6, c2 = (i & 63) * 2;
      f32x2 t = *(const f32x2*)&ap[p * PLANE + (size_t)(row0 + rr) * HH + c2];
      *(unsigned*)&sh_a[p][rr][c2] = (unsigned)f2bf(t.x) | ((unsigned)f2bf(t.y) << 16);
    }
  __syncthreads();
  f32x4 Ch[2][2], Cx[2][2], Cy[2][2], Cz[2][2];
#pragma unroll
  for (int mt = 0; mt < 2; ++mt)
#pragma unroll
    for (int nt = 0; nt < 2; ++nt) {
      Ch[mt][nt] = (f32x4){0,0,0,0}; Cx[mt][nt] = (f32x4){0,0,0,0};
      Cy[mt][nt] = (f32x4){0,0,0,0}; Cz[mt][nt] = (f32x4){0,0,0,0};
    }
  gemm32(sh_a[0], Wpack + 3 * 16384, w, nlo, quad, Ch);
  gemm32(sh_a[1], Wpack + 5 * 16384, w, nlo, quad, Cx);
  gemm32(sh_a[2], Wpack + 5 * 16384, w, nlo, quad, Cy);
  gemm32(sh_a[3], Wpack + 5 * 16384, w, nlo, quad, Cz);
  // epilogue: h -> bf16 LDS; vin += into Cv regs
#pragma unroll
  for (int mt = 0; mt < 2; ++mt)
#pragma unroll
    for (int nt = 0; nt < 2; ++nt)
#pragma unroll
      for (int reg = 0; reg < 4; ++reg) {
        int rl = mt * 16 + quad * 4 + reg;
        size_t row = row0 + rl;
        int col = w * 32 + nt * 16 + nlo;
        sh_h[rl][col] = f2bf(hin[row * HH + col] + Ch[mt][nt][reg]);
        Cx[mt][nt][reg] += vp[0 * PLANE + row * HH + col];
        Cy[mt][nt][reg] += vp[1 * PLANE + row * HH + col];
        Cz[mt][nt][reg] += vp[2 * PLANE + row * HH + col];
      }
  __syncthreads();   // sh_h ready; all sh_a reads done -> sh_a[0] free to alias
  unsigned short (*sh_q)[136] = sh_a[0];
  f32x4 Cq[2][2];
#pragma unroll
  for (int mt = 0; mt < 2; ++mt)
#pragma unroll
    for (int nt = 0; nt < 2; ++nt) Cq[mt][nt] = (f32x4){0,0,0,0};
  gemm32(sh_h, Wpack + 6 * 16384, w, nlo, quad, Cq);
#pragma unroll
  for (int mt = 0; mt < 2; ++mt)
#pragma unroll
    for (int nt = 0; nt < 2; ++nt)
#pragma unroll
      for (int reg = 0; reg < 4; ++reg)
        sh_q[mt * 16 + quad * 4 + reg][w * 32 + nt * 16 + nlo] = f2bf(silu_f(Cq[mt][nt][reg]));
  __syncthreads();
  f32x4 Cg[2][2];
#pragma unroll
  for (int mt = 0; mt < 2; ++mt)
#pragma unroll
    for (int nt = 0; nt < 2; ++nt) Cg[mt][nt] = (f32x4){0,0,0,0};
  gemm32(sh_q, Wpack + 7 * 16384, w, nlo, quad, Cg);
  // contraction: per-row sums of g*v over this wave's 32 cols
  float pr[3][2][4];
#pragma unroll
  for (int d = 0; d < 3; ++d)
#pragma unroll
    for (int mt = 0; mt < 2; ++mt)
#pragma unroll
      for (int reg = 0; reg < 4; ++reg) pr[d][mt][reg] = 0.f;
#pragma unroll
  for (int mt = 0; mt < 2; ++mt)
#pragma unroll
    for (int nt = 0; nt < 2; ++nt)
#pragma unroll
      for (int reg = 0; reg < 4; ++reg) {
        float gv = Cg[mt][nt][reg];
        pr[0][mt][reg] += gv * Cx[mt][nt][reg];
        pr[1][mt][reg] += gv * Cy[mt][nt][reg];
        pr[2][mt][reg] += gv * Cz[mt][nt][reg];
      }
#pragma unroll
  for (int off = 1; off < 16; off <<= 1)
#pragma unroll
    for (int d = 0; d < 3; ++d)
#pragma unroll
      for (int mt = 0; mt < 2; ++mt)
#pragma unroll
        for (int reg = 0; reg < 4; ++reg)
          pr[d][mt][reg] += __shfl_xor(pr[d][mt][reg], off);
  if (nlo == 0) {
#pragma unroll
    for (int d = 0; d < 3; ++d)
#pragma unroll
      for (int mt = 0; mt < 2; ++mt)
#pragma unroll
        for (int reg = 0; reg < 4; ++reg)
          red[w][mt * 16 + quad * 4 + reg][d] = pr[d][mt][reg];
  }
  __syncthreads();
  if (tid < 96) {
    int row = tid / 3, d = tid % 3;
    float s = red[0][row][d] + red[1][row][d] + red[2][row][d] + red[3][row][d];
    out[(size_t)(row0 + row) * 3 + d] = s * fs[0];
  }
}

extern "C" void kernel_launch(void* const* d_in, const int* in_sizes, int n_in,
                              void* d_out, int out_size, void* d_ws, size_t ws_size,
                              hipStream_t stream) {
  const float* pos  = (const float*)d_in[0];
  const int*   z    = (const int*)d_in[1];
  const float* gf   = (const float*)d_in[2];
  const float* emb  = (const float*)d_in[3];
  const float* Wt   = (const float*)d_in[4];
  const float* Wr1  = (const float*)d_in[5];
  const float* Wr2  = (const float*)d_in[6];
  const float* Wupd = (const float*)d_in[7];
  const float* Wmix = (const float*)d_in[8];
  const float* Wg1  = (const float*)d_in[9];
  const float* Wg2  = (const float*)d_in[10];
  const float* fs   = (const float*)d_in[11];
  float* out = (float*)d_out;

  float* ws = (float*)d_ws;
  float* hA = ws;                            // 2 MB
  float* hB = ws + PLANE;                    // 2 MB
  float* vp = ws + 2 * PLANE;                // 6 MB (3 planes)
  float* apl = ws + 5 * PLANE;               // 8 MB (4 planes)
  unsigned short* Wpack = (unsigned short*)(ws + 9 * PLANE);  // 256 KB

  k_init<<<dim3(BB), dim3(256), 0, stream>>>(emb, z, gf, Wt, Wr2, Wupd, Wmix,
                                             Wg1, Wg2, hA, Wpack);
  k_layer<<<dim3(NROW), dim3(256), 0, stream>>>(pos, hA, apl, Wr1, Wpack, 0);
  k_update<<<dim3(128), dim3(256), 0, stream>>>(apl, hA, hB, vp, Wpack);
  k_layer<<<dim3(NROW), dim3(256), 0, stream>>>(pos, hB, apl, Wr1, Wpack, 1);
  k_update_ro<<<dim3(128), dim3(256), 0, stream>>>(apl, hB, vp, Wpack, fs, out);
}

// Round 8
// 167.186 us; speedup vs baseline: 1.3257x; 1.0528x over previous
//
#include <hip/hip_runtime.h>
#include <math.h>

#define NN 64      // nodes per graph
#define HH 128     // hidden channels
#define NBB 8      // bessel basis
#define TT 32      // time embedding dim
#define BB 64      // batch
#define NROW (BB * NN)        // 4096 total rows
#define PLANE ((size_t)NROW * HH)   // 524288
#define WR1OFF (8 * 16384)    // Wr1 B-frag slabs in Wpack (2 x 4096)

typedef __attribute__((ext_vector_type(8))) short short8;
typedef __attribute__((ext_vector_type(4))) float f32x4;
typedef __attribute__((ext_vector_type(2))) float f32x2;

__device__ __forceinline__ float silu_f(float x) {
  return x * __builtin_amdgcn_rcpf(1.0f + __expf(-x));
}

__device__ __forceinline__ unsigned short f2bf(float x) {
  union { float f; unsigned u; } v; v.f = x;
  unsigned r = v.u + 0x7FFFu + ((v.u >> 16) & 1u);   // round-to-nearest-even
  return (unsigned short)(r >> 16);
}

// 32-row MFMA GEMM tile: C[2][2] += shA[32][128(136)] @ B (packed frag order).
// Wave w owns cols w*32..w*32+31. C mapping: row=mt*16+quad*4+reg, col=w*32+nt*16+nlo.
__device__ __forceinline__ void gemm32(
    const unsigned short (*sA)[136], const unsigned short* __restrict__ Bp,
    int w, int nlo, int quad, f32x4 C[2][2]) {
  short8 bfr[4][2];
#pragma unroll
  for (int kt = 0; kt < 4; ++kt)
#pragma unroll
    for (int nt = 0; nt < 2; ++nt)
      bfr[kt][nt] = *(const short8*)&Bp[((kt * 128 + w * 32 + nt * 16 + nlo) * 4 + quad) * 8];
#pragma unroll
  for (int mt = 0; mt < 2; ++mt) {
    short8 afr[4];
#pragma unroll
    for (int kt = 0; kt < 4; ++kt)
      afr[kt] = *(const short8*)&sA[mt * 16 + nlo][kt * 32 + quad * 8];
#pragma unroll
    for (int nt = 0; nt < 2; ++nt)
#pragma unroll
      for (int kt = 0; kt < 4; ++kt)
        C[mt][nt] = __builtin_amdgcn_mfma_f32_16x16x32_bf16(afr[kt], bfr[kt][nt], C[mt][nt], 0, 0, 0);
  }
}

// Grid 64. Pack all weights -> bf16 MFMA-B-frag order; init h.
// Wpack slots: [0,1]=Wr2 l0/l1, [2,3]=Wupd, [4,5]=Wmix, [6]=Wg1, [7]=Wg2,
// then 2 x 4096 zero-padded (K=8 of 32) Wr1 slabs at WR1OFF.
__global__ __launch_bounds__(256) void k_init(
    const float* __restrict__ emb, const int* __restrict__ z,
    const float* __restrict__ gf, const float* __restrict__ Wt,
    const float* __restrict__ Wr1, const float* __restrict__ Wr2,
    const float* __restrict__ Wupd, const float* __restrict__ Wmix,
    const float* __restrict__ Wg1, const float* __restrict__ Wg2,
    float* __restrict__ h, unsigned short* __restrict__ Wpack) {
  __shared__ float tvec[HH];
  __shared__ int sz[NN];
  int b = blockIdx.x, tid = threadIdx.x;
#pragma unroll
  for (int ii = 0; ii < 8; ++ii) {
    int idx = b * 2048 + ii * 256 + tid;    // 0..131071
    int m = idx >> 14;
    int local = idx & 16383;
    float val;
    if (m < 2) val = Wr2[idx];
    else if (m < 4) val = Wupd[idx - 32768];
    else if (m < 6) val = Wmix[idx - 65536];
    else if (m == 6) val = Wg1[local];
    else val = Wg2[local];
    int k = local >> 7, n = local & 127;
    int kt = k >> 5, q = (k >> 3) & 3, j = k & 7;
    Wpack[(idx & ~16383) + (((kt * 128 + n) * 4 + q) * 8) + j] = f2bf(val);
  }
  if (tid < 128) {                          // Wr1 zero-padded B-frags (kt=0 only)
    int e = b * 128 + tid;                  // 0..8191 over the 64 blocks
    int l = e >> 12, p = e & 4095;          // p = (n*4+q)*8+j
    int n = p >> 5, q = (p >> 3) & 3, j = p & 7;
    float val = (q == 0) ? Wr1[l * NBB * HH + j * HH + n] : 0.f;
    Wpack[WR1OFF + l * 4096 + p] = f2bf(val);
  }
  if (tid < NN) sz[tid] = z[b * NN + tid];
  if (tid < HH) {
    float acc = 0.f;
#pragma unroll
    for (int k = 0; k < TT; ++k) acc += gf[b * TT + k] * Wt[k * HH + tid];
    tvec[tid] = acc;
  }
  __syncthreads();
  for (int i = tid; i < NN * HH; i += 256) {
    int n = i >> 7, c = i & 127;
    h[(size_t)b * NN * HH + i] = emb[sz[n] * HH + c] + tvec[c];
  }
}

// One block (256 thr = 4 waves) per (b, receiver r). Writes a-planes:
// ap[0]=a0, ap[1]=a1x, ap[2]=a1y, ap[3]=a1z, each [4096][128] fp32.
// Stage A: geometry -> u (LDS), rb -> bf16 A-frag rows (LDS).
// Stage B: S = silu(rb@Wr1) via MFMA (K=8 zero-padded to 32), silu on C-regs,
//          round-trip to sh_S in main-GEMM A-layout.
// Main GEMM: w = S@Wr2 via MFMA; epilogue m0=w*h, u-weight, quad-reduce.
__global__ __launch_bounds__(256) void k_layer(
    const float* __restrict__ pos,
    const float* __restrict__ hin,
    float* __restrict__ ap,
    const unsigned short* __restrict__ Wpack,
    int l) {
  __shared__ __align__(16) unsigned short sh_S[NN][136];
  __shared__ __align__(16) unsigned short sh_rbh[NN][8];   // bf16 rb, A-frag rows
  __shared__ __align__(16) float sh_u[3][NN];

  int blk = blockIdx.x;          // b*NN + r
  int b = blk >> 6, r = blk & 63;
  int tid = threadIdx.x;
  int w = tid >> 6, lane = tid & 63;
  int nlo = lane & 15, quad = lane >> 4;

  // ---- Stage A: geometry + bessel, flat over all 256 threads ----
  {
    int s = tid & 63, ksel = tid >> 6;    // each thread: one sender, two basis terms
    const float* pb = pos + b * NN * 3;
    float dx = pb[r * 3 + 0] - pb[s * 3 + 0];
    float dy = pb[r * 3 + 1] - pb[s * 3 + 1];
    float dz = pb[r * 3 + 2] - pb[s * 3 + 2];
    float rr = sqrtf(dx * dx + dy * dy + dz * dz + 1e-12f);
    float inv = __builtin_amdgcn_rcpf(rr);
    if (ksel == 0) {
      sh_u[0][s] = dx * inv; sh_u[1][s] = dy * inv; sh_u[2][s] = dz * inv;
    }
    const float PI_OVER_5 = 0.628318530717958647692f;
    float fc = (s != r && rr < 5.0f) ? 0.5f * (__cosf(PI_OVER_5 * rr) + 1.0f) : 0.0f;
    float base = PI_OVER_5 * rr;
    float sc = inv * fc;
    float r0 = __sinf((float)(ksel * 2 + 1) * base) * sc;
    float r1 = __sinf((float)(ksel * 2 + 2) * base) * sc;
    *(unsigned*)&sh_rbh[s][ksel * 2] = (unsigned)f2bf(r0) | ((unsigned)f2bf(r1) << 16);
  }
  __syncthreads();

  // ---- Stage B: S = silu(rb @ Wr1) via MFMA; wave w owns cols w*32..w*32+31 ----
  {
    const unsigned short* Wr1p = Wpack + WR1OFF + l * 4096;
    short8 bw[2];
#pragma unroll
    for (int nt = 0; nt < 2; ++nt)
      bw[nt] = *(const short8*)&Wr1p[((w * 32 + nt * 16 + nlo) * 4 + quad) * 8];
    const short8 zero8 = {0, 0, 0, 0, 0, 0, 0, 0};
#pragma unroll
    for (int mtp = 0; mtp < 2; ++mtp) {     // two mt-halves to cap acc-reg use
      f32x4 Cs[2][2];
#pragma unroll
      for (int mi = 0; mi < 2; ++mi)
#pragma unroll
        for (int nt = 0; nt < 2; ++nt) Cs[mi][nt] = (f32x4){0.f, 0.f, 0.f, 0.f};
#pragma unroll
      for (int mi = 0; mi < 2; ++mi) {
        int mt = mtp * 2 + mi;
        short8 afr = (quad == 0) ? *(const short8*)&sh_rbh[mt * 16 + nlo][0] : zero8;
#pragma unroll
        for (int nt = 0; nt < 2; ++nt)
          Cs[mi][nt] = __builtin_amdgcn_mfma_f32_16x16x32_bf16(afr, bw[nt], Cs[mi][nt], 0, 0, 0);
      }
#pragma unroll
      for (int mi = 0; mi < 2; ++mi)
#pragma unroll
        for (int nt = 0; nt < 2; ++nt)
#pragma unroll
          for (int reg = 0; reg < 4; ++reg) {
            int s = (mtp * 2 + mi) * 16 + quad * 4 + reg;
            int c = w * 32 + nt * 16 + nlo;
            sh_S[s][c] = f2bf(silu_f(Cs[mi][nt][reg]));
          }
    }
  }
  __syncthreads();

  // ---- Main GEMM + message epilogue (wave w owns c in [w*32, w*32+32)) ----
  const unsigned short* Bbase = Wpack + l * 16384;
  short8 bfr[4][2];
#pragma unroll
  for (int kt = 0; kt < 4; ++kt)
#pragma unroll
    for (int nt = 0; nt < 2; ++nt) {
      int c = w * 32 + nt * 16 + nlo;
      bfr[kt][nt] = *(const short8*)&Bbase[((kt * 128 + c) * 4 + quad) * 8];
    }
  float acc0[2] = {0.f, 0.f};
  float a1x[2] = {0.f, 0.f};
  float a1y[2] = {0.f, 0.f};
  float a1z[2] = {0.f, 0.f};
  const float* hb = hin + (size_t)b * NN * HH;

#pragma unroll
  for (int mt = 0; mt < 4; ++mt) {
    short8 afr[4];
    int s_a = mt * 16 + nlo;
#pragma unroll
    for (int kt = 0; kt < 4; ++kt)
      afr[kt] = *(const short8*)&sh_S[s_a][kt * 32 + quad * 8];
    float ux[4], uy[4], uz[4];
#pragma unroll
    for (int reg = 0; reg < 4; ++reg) {
      int s = mt * 16 + quad * 4 + reg;
      ux[reg] = sh_u[0][s]; uy[reg] = sh_u[1][s]; uz[reg] = sh_u[2][s];
    }
#pragma unroll
    for (int nt = 0; nt < 2; ++nt) {
      int c = w * 32 + nt * 16 + nlo;
      f32x4 C = {0.f, 0.f, 0.f, 0.f};
#pragma unroll
      for (int kt = 0; kt < 4; ++kt)
        C = __builtin_amdgcn_mfma_f32_16x16x32_bf16(afr[kt], bfr[kt][nt], C, 0, 0, 0);
#pragma unroll
      for (int reg = 0; reg < 4; ++reg) {
        int s = mt * 16 + quad * 4 + reg;
        float m0 = C[reg] * hb[s * HH + c];
        acc0[nt] += m0;
        a1x[nt] += m0 * ux[reg];
        a1y[nt] += m0 * uy[reg];
        a1z[nt] += m0 * uz[reg];
      }
    }
  }

  const float invAvg = 1.0f / 63.0f;
#pragma unroll
  for (int nt = 0; nt < 2; ++nt) {
    float q0 = acc0[nt], q1 = a1x[nt], q2 = a1y[nt], q3 = a1z[nt];
    q0 += __shfl_xor(q0, 16); q0 += __shfl_xor(q0, 32);
    q1 += __shfl_xor(q1, 16); q1 += __shfl_xor(q1, 32);
    q2 += __shfl_xor(q2, 16); q2 += __shfl_xor(q2, 32);
    q3 += __shfl_xor(q3, 16); q3 += __shfl_xor(q3, 32);
    if (quad == 0) {
      size_t base = (size_t)blk * HH + w * 32 + nt * 16 + nlo;
      ap[base]             = q0 * invAvg;
      ap[PLANE + base]     = q1 * invAvg;
      ap[2 * PLANE + base] = q2 * invAvg;
      ap[3 * PLANE + base] = q3 * invAvg;
    }
  }
}

// Layer-0 node update via MFMA, 32 rows/block (grid 128):
// hout = hin + a0@Wupd0 ; v planes = a1@Wmix0.
__global__ __launch_bounds__(256) void k_update(
    const float* __restrict__ ap, const float* __restrict__ hin,
    float* __restrict__ hout, float* __restrict__ vp,
    const unsigned short* __restrict__ Wpack) {
  __shared__ __align__(16) unsigned short sh_a[4][32][136];
  int tid = threadIdx.x, w = tid >> 6, lane = tid & 63;
  int nlo = lane & 15, quad = lane >> 4;
  int row0 = blockIdx.x * 32;
#pragma unroll
  for (int p = 0; p < 4; ++p)
    for (int i = tid; i < 32 * 64; i += 256) {
      int rr = i >> 6, c2 = (i & 63) * 2;
      f32x2 t = *(const f32x2*)&ap[p * PLANE + (size_t)(row0 + rr) * HH + c2];
      *(unsigned*)&sh_a[p][rr][c2] = (unsigned)f2bf(t.x) | ((unsigned)f2bf(t.y) << 16);
    }
  __syncthreads();
  f32x4 Ch[2][2], Cx[2][2], Cy[2][2], Cz[2][2];
#pragma unroll
  for (int mt = 0; mt < 2; ++mt)
#pragma unroll
    for (int nt = 0; nt < 2; ++nt) {
      Ch[mt][nt] = (f32x4){0,0,0,0}; Cx[mt][nt] = (f32x4){0,0,0,0};
      Cy[mt][nt] = (f32x4){0,0,0,0}; Cz[mt][nt] = (f32x4){0,0,0,0};
    }
  gemm32(sh_a[0], Wpack + 2 * 16384, w, nlo, quad, Ch);
  gemm32(sh_a[1], Wpack + 4 * 16384, w, nlo, quad, Cx);
  gemm32(sh_a[2], Wpack + 4 * 16384, w, nlo, quad, Cy);
  gemm32(sh_a[3], Wpack + 4 * 16384, w, nlo, quad, Cz);
#pragma unroll
  for (int mt = 0; mt < 2; ++mt)
#pragma unroll
    for (int nt = 0; nt < 2; ++nt)
#pragma unroll
      for (int reg = 0; reg < 4; ++reg) {
        size_t row = row0 + mt * 16 + quad * 4 + reg;
        int col = w * 32 + nt * 16 + nlo;
        hout[row * HH + col] = hin[row * HH + col] + Ch[mt][nt][reg];
        vp[0 * PLANE + row * HH + col] = Cx[mt][nt][reg];
        vp[1 * PLANE + row * HH + col] = Cy[mt][nt][reg];
        vp[2 * PLANE + row * HH + col] = Cz[mt][nt][reg];
      }
}

// Layer-1 update + full readout, 32 rows/block (grid 128), 7 MFMA GEMMs in-block:
// h = hin + a0@Wupd1; v = vin + a1@Wmix1; g = silu(h@Wg1)@Wg2;
// out[row,d] = sum_c v[row,c,d]*g[row,c] * fs.
__global__ __launch_bounds__(256) void k_update_ro(
    const float* __restrict__ ap, const float* __restrict__ hin,
    const float* __restrict__ vp,
    const unsigned short* __restrict__ Wpack,
    const float* __restrict__ fs, float* __restrict__ out) {
  __shared__ __align__(16) unsigned short sh_a[4][32][136];   // a-tiles; [0] aliased by q
  __shared__ __align__(16) unsigned short sh_h[32][136];
  __shared__ float red[4][32][3];
  int tid = threadIdx.x, w = tid >> 6, lane = tid & 63;
  int nlo = lane & 15, quad = lane >> 4;
  int row0 = blockIdx.x * 32;
#pragma unroll
  for (int p = 0; p < 4; ++p)
    for (int i = tid; i < 32 * 64; i += 256) {
      int rr = i >> 6, c2 = (i & 63) * 2;
      f32x2 t = *(const f32x2*)&ap[p * PLANE + (size_t)(row0 + rr) * HH + c2];
      *(unsigned*)&sh_a[p][rr][c2] = (unsigned)f2bf(t.x) | ((unsigned)f2bf(t.y) << 16);
    }
  __syncthreads();
  f32x4 Ch[2][2], Cx[2][2], Cy[2][2], Cz[2][2];
#pragma unroll
  for (int mt = 0; mt < 2; ++mt)
#pragma unroll
    for (int nt = 0; nt < 2; ++nt) {
      Ch[mt][nt] = (f32x4){0,0,0,0}; Cx[mt][nt] = (f32x4){0,0,0,0};
      Cy[mt][nt] = (f32x4){0,0,0,0}; Cz[mt][nt] = (f32x4){0,0,0,0};
    }
  gemm32(sh_a[0], Wpack + 3 * 16384, w, nlo, quad, Ch);
  gemm32(sh_a[1], Wpack + 5 * 16384, w, nlo, quad, Cx);
  gemm32(sh_a[2], Wpack + 5 * 16384, w, nlo, quad, Cy);
  gemm32(sh_a[3], Wpack + 5 * 16384, w, nlo, quad, Cz);
  // epilogue: h -> bf16 LDS; vin += into Cv regs
#pragma unroll
  for (int mt = 0; mt < 2; ++mt)
#pragma unroll
    for (int nt = 0; nt < 2; ++nt)
#pragma unroll
      for (int reg = 0; reg < 4; ++reg) {
        int rl = mt * 16 + quad * 4 + reg;
        size_t row = row0 + rl;
        int col = w * 32 + nt * 16 + nlo;
        sh_h[rl][col] = f2bf(hin[row * HH + col] + Ch[mt][nt][reg]);
        Cx[mt][nt][reg] += vp[0 * PLANE + row * HH + col];
        Cy[mt][nt][reg] += vp[1 * PLANE + row * HH + col];
        Cz[mt][nt][reg] += vp[2 * PLANE + row * HH + col];
      }
  __syncthreads();   // sh_h ready; all sh_a reads done -> sh_a[0] free to alias
  unsigned short (*sh_q)[136] = sh_a[0];
  f32x4 Cq[2][2];
#pragma unroll
  for (int mt = 0; mt < 2; ++mt)
#pragma unroll
    for (int nt = 0; nt < 2; ++nt) Cq[mt][nt] = (f32x4){0,0,0,0};
  gemm32(sh_h, Wpack + 6 * 16384, w, nlo, quad, Cq);
#pragma unroll
  for (int mt = 0; mt < 2; ++mt)
#pragma unroll
    for (int nt = 0; nt < 2; ++nt)
#pragma unroll
      for (int reg = 0; reg < 4; ++reg)
        sh_q[mt * 16 + quad * 4 + reg][w * 32 + nt * 16 + nlo] = f2bf(silu_f(Cq[mt][nt][reg]));
  __syncthreads();
  f32x4 Cg[2][2];
#pragma unroll
  for (int mt = 0; mt < 2; ++mt)
#pragma unroll
    for (int nt = 0; nt < 2; ++nt) Cg[mt][nt] = (f32x4){0,0,0,0};
  gemm32(sh_q, Wpack + 7 * 16384, w, nlo, quad, Cg);
  // contraction: per-row sums of g*v over this wave's 32 cols
  float pr[3][2][4];
#pragma unroll
  for (int d = 0; d < 3; ++d)
#pragma unroll
    for (int mt = 0; mt < 2; ++mt)
#pragma unroll
      for (int reg = 0; reg < 4; ++reg) pr[d][mt][reg] = 0.f;
#pragma unroll
  for (int mt = 0; mt < 2; ++mt)
#pragma unroll
    for (int nt = 0; nt < 2; ++nt)
#pragma unroll
      for (int reg = 0; reg < 4; ++reg) {
        float gv = Cg[mt][nt][reg];
        pr[0][mt][reg] += gv * Cx[mt][nt][reg];
        pr[1][mt][reg] += gv * Cy[mt][nt][reg];
        pr[2][mt][reg] += gv * Cz[mt][nt][reg];
      }
#pragma unroll
  for (int off = 1; off < 16; off <<= 1)
#pragma unroll
    for (int d = 0; d < 3; ++d)
#pragma unroll
      for (int mt = 0; mt < 2; ++mt)
#pragma unroll
        for (int reg = 0; reg < 4; ++reg)
          pr[d][mt][reg] += __shfl_xor(pr[d][mt][reg], off);
  if (nlo == 0) {
#pragma unroll
    for (int d = 0; d < 3; ++d)
#pragma unroll
      for (int mt = 0; mt < 2; ++mt)
#pragma unroll
        for (int reg = 0; reg < 4; ++reg)
          red[w][mt * 16 + quad * 4 + reg][d] = pr[d][mt][reg];
  }
  __syncthreads();
  if (tid < 96) {
    int row = tid / 3, d = tid % 3;
    float s = red[0][row][d] + red[1][row][d] + red[2][row][d] + red[3][row][d];
    out[(size_t)(row0 + row) * 3 + d] = s * fs[0];
  }
}

extern "C" void kernel_launch(void* const* d_in, const int* in_sizes, int n_in,
                              void* d_out, int out_size, void* d_ws, size_t ws_size,
                              hipStream_t stream) {
  const float* pos  = (const float*)d_in[0];
  const int*   z    = (const int*)d_in[1];
  const float* gf   = (const float*)d_in[2];
  const float* emb  = (const float*)d_in[3];
  const float* Wt   = (const float*)d_in[4];
  const float* Wr1  = (const float*)d_in[5];
  const float* Wr2  = (const float*)d_in[6];
  const float* Wupd = (const float*)d_in[7];
  const float* Wmix = (const float*)d_in[8];
  const float* Wg1  = (const float*)d_in[9];
  const float* Wg2  = (const float*)d_in[10];
  const float* fs   = (const float*)d_in[11];
  float* out = (float*)d_out;

  float* ws = (float*)d_ws;
  float* hA = ws;                            // 2 MB
  float* hB = ws + PLANE;                    // 2 MB
  float* vp = ws + 2 * PLANE;                // 6 MB (3 planes)
  float* apl = ws + 5 * PLANE;               // 8 MB (4 planes)
  unsigned short* Wpack = (unsigned short*)(ws + 9 * PLANE);  // 272 KB

  k_init<<<dim3(BB), dim3(256), 0, stream>>>(emb, z, gf, Wt, Wr1, Wr2, Wupd,
                                             Wmix, Wg1, Wg2, hA, Wpack);
  k_layer<<<dim3(NROW), dim3(256), 0, stream>>>(pos, hA, apl, Wpack, 0);
  k_update<<<dim3(128), dim3(256), 0, stream>>>(apl, hA, hB, vp, Wpack);
  k_layer<<<dim3(NROW), dim3(256), 0, stream>>>(pos, hB, apl, Wpack, 1);
  k_update_ro<<<dim3(128), dim3(256), 0, stream>>>(apl, hB, vp, Wpack, fs, out);
}

// Round 9
// 155.575 us; speedup vs baseline: 1.4247x; 1.0746x over previous
//
#include <hip/hip_runtime.h>
#include <math.h>

#define NN 64      // nodes per graph
#define HH 128     // hidden channels
#define NBB 8      // bessel basis
#define TT 32      // time embedding dim
#define BB 64      // batch
#define NROW (BB * NN)        // 4096 total rows
#define PLANE ((size_t)NROW * HH)   // 524288
#define WR1OFF (8 * 16384)    // Wr1 B-frag slabs in Wpack (2 x 4096)

typedef __attribute__((ext_vector_type(8))) short short8;
typedef __attribute__((ext_vector_type(4))) float f32x4;
typedef __attribute__((ext_vector_type(2))) float f32x2;

__device__ __forceinline__ float silu_f(float x) {
  return x * __builtin_amdgcn_rcpf(1.0f + __expf(-x));
}

__device__ __forceinline__ unsigned short f2bf(float x) {
  union { float f; unsigned u; } v; v.f = x;
  unsigned r = v.u + 0x7FFFu + ((v.u >> 16) & 1u);   // round-to-nearest-even
  return (unsigned short)(r >> 16);
}

// 16-row MFMA GEMM tile: C[2] += sA[16][136] @ B (packed frag order).
// Wave w owns cols w*32..w*32+31. C map: row=quad*4+reg, col=w*32+nt*16+nlo.
__device__ __forceinline__ void gemm16(
    const unsigned short (*sA)[136], const unsigned short* __restrict__ Bp,
    int w, int nlo, int quad, f32x4 C[2]) {
  short8 afr[4];
#pragma unroll
  for (int kt = 0; kt < 4; ++kt)
    afr[kt] = *(const short8*)&sA[nlo][kt * 32 + quad * 8];
#pragma unroll
  for (int nt = 0; nt < 2; ++nt)
#pragma unroll
    for (int kt = 0; kt < 4; ++kt) {
      short8 bfr = *(const short8*)&Bp[((kt * 128 + w * 32 + nt * 16 + nlo) * 4 + quad) * 8];
      C[nt] = __builtin_amdgcn_mfma_f32_16x16x32_bf16(afr[kt], bfr, C[nt], 0, 0, 0);
    }
}

// Grid 64. Pack all weights -> bf16 MFMA-B-frag order; init h.
// Wpack slots: [0,1]=Wr2 l0/l1, [2,3]=Wupd, [4,5]=Wmix, [6]=Wg1, [7]=Wg2,
// then 2 x 4096 zero-padded (K=8 of 32) Wr1 slabs at WR1OFF.
__global__ __launch_bounds__(256) void k_init(
    const float* __restrict__ emb, const int* __restrict__ z,
    const float* __restrict__ gf, const float* __restrict__ Wt,
    const float* __restrict__ Wr1, const float* __restrict__ Wr2,
    const float* __restrict__ Wupd, const float* __restrict__ Wmix,
    const float* __restrict__ Wg1, const float* __restrict__ Wg2,
    float* __restrict__ h, unsigned short* __restrict__ Wpack) {
  __shared__ float tvec[HH];
  __shared__ int sz[NN];
  int b = blockIdx.x, tid = threadIdx.x;
#pragma unroll
  for (int ii = 0; ii < 8; ++ii) {
    int idx = b * 2048 + ii * 256 + tid;    // 0..131071
    int m = idx >> 14;
    int local = idx & 16383;
    float val;
    if (m < 2) val = Wr2[idx];
    else if (m < 4) val = Wupd[idx - 32768];
    else if (m < 6) val = Wmix[idx - 65536];
    else if (m == 6) val = Wg1[local];
    else val = Wg2[local];
    int k = local >> 7, n = local & 127;
    int kt = k >> 5, q = (k >> 3) & 3, j = k & 7;
    Wpack[(idx & ~16383) + (((kt * 128 + n) * 4 + q) * 8) + j] = f2bf(val);
  }
  if (tid < 128) {                          // Wr1 zero-padded B-frags (kt=0 only)
    int e = b * 128 + tid;                  // 0..8191 over the 64 blocks
    int l = e >> 12, p = e & 4095;          // p = (n*4+q)*8+j
    int n = p >> 5, q = (p >> 3) & 3, j = p & 7;
    float val = (q == 0) ? Wr1[l * NBB * HH + j * HH + n] : 0.f;
    Wpack[WR1OFF + l * 4096 + p] = f2bf(val);
  }
  if (tid < NN) sz[tid] = z[b * NN + tid];
  if (tid < HH) {
    float acc = 0.f;
#pragma unroll
    for (int k = 0; k < TT; ++k) acc += gf[b * TT + k] * Wt[k * HH + tid];
    tvec[tid] = acc;
  }
  __syncthreads();
  for (int i = tid; i < NN * HH; i += 256) {
    int n = i >> 7, c = i & 127;
    h[(size_t)b * NN * HH + i] = emb[sz[n] * HH + c] + tvec[c];
  }
}

// One block (256 thr = 4 waves) per (b, receiver-pair {2rp, 2rp+1}).
// Stage A: geometry -> u, rb -> bf16 A-frag rows, both receivers.
// Stage B: S_ri = silu(rb_ri@Wr1) via MFMA, silu on C-regs -> sh_S[ri].
// Main: w = S_ri@Wr2 via MFMA; epilogue m0=w*hb (hb regs shared across ri),
// u-weight, quad-reduce, write a-planes.
__global__ __launch_bounds__(256) void k_layer(
    const float* __restrict__ pos,
    const float* __restrict__ hin,
    float* __restrict__ ap,
    const unsigned short* __restrict__ Wpack,
    int l) {
  __shared__ __align__(16) unsigned short sh_S[2][NN][136];   // 34.8 KB
  __shared__ __align__(16) unsigned short sh_rbh[2][NN][8];   // bf16 rb A-frag rows
  __shared__ __align__(16) float sh_u[2][3][NN];

  int blk = blockIdx.x;          // b*32 + rp
  int b = blk >> 5, rp = blk & 31;
  int r0 = rp * 2;
  int tid = threadIdx.x;
  int w = tid >> 6, lane = tid & 63;
  int nlo = lane & 15, quad = lane >> 4;
  const float* hb = hin + (size_t)b * NN * HH;

  // ---- epilogue hb prefetch (independent of LDS; drains at first barrier) ----
  float hbv[4][2][4];
#pragma unroll
  for (int mt = 0; mt < 4; ++mt)
#pragma unroll
    for (int nt = 0; nt < 2; ++nt)
#pragma unroll
      for (int reg = 0; reg < 4; ++reg)
        hbv[mt][nt][reg] = hb[(mt * 16 + quad * 4 + reg) * HH + w * 32 + nt * 16 + nlo];

  // ---- Stage A: geometry + bessel; thread = (ri, ksel, s) ----
  {
    int s = tid & 63;
    int ksel = (tid >> 6) & 1;           // which 4 of 8 basis terms
    int ri = (tid >> 7) & 1;
    int r = r0 + ri;
    const float* pb = pos + b * NN * 3;
    float dx = pb[r * 3 + 0] - pb[s * 3 + 0];
    float dy = pb[r * 3 + 1] - pb[s * 3 + 1];
    float dz = pb[r * 3 + 2] - pb[s * 3 + 2];
    float rr = sqrtf(dx * dx + dy * dy + dz * dz + 1e-12f);
    float inv = __builtin_amdgcn_rcpf(rr);
    if (ksel == 0) {
      sh_u[ri][0][s] = dx * inv; sh_u[ri][1][s] = dy * inv; sh_u[ri][2][s] = dz * inv;
    }
    const float PI_OVER_5 = 0.628318530717958647692f;
    float fc = (s != r && rr < 5.0f) ? 0.5f * (__cosf(PI_OVER_5 * rr) + 1.0f) : 0.0f;
    float base = PI_OVER_5 * rr;
    float sc = inv * fc;
    int k0 = ksel * 4;
    float v0 = __sinf((float)(k0 + 1) * base) * sc;
    float v1 = __sinf((float)(k0 + 2) * base) * sc;
    float v2 = __sinf((float)(k0 + 3) * base) * sc;
    float v3 = __sinf((float)(k0 + 4) * base) * sc;
    *(unsigned*)&sh_rbh[ri][s][k0]     = (unsigned)f2bf(v0) | ((unsigned)f2bf(v1) << 16);
    *(unsigned*)&sh_rbh[ri][s][k0 + 2] = (unsigned)f2bf(v2) | ((unsigned)f2bf(v3) << 16);
  }
  __syncthreads();

  // ---- Stage B: S_ri = silu(rb_ri @ Wr1) via MFMA (K=8 zero-padded) ----
  {
    const unsigned short* Wr1p = Wpack + WR1OFF + l * 4096;
    short8 bw[2];
#pragma unroll
    for (int nt = 0; nt < 2; ++nt)
      bw[nt] = *(const short8*)&Wr1p[((w * 32 + nt * 16 + nlo) * 4 + quad) * 8];
    const short8 zero8 = {0, 0, 0, 0, 0, 0, 0, 0};
#pragma unroll
    for (int ri = 0; ri < 2; ++ri)
#pragma unroll
      for (int mtp = 0; mtp < 2; ++mtp) {   // two mt-halves cap acc-reg use
        f32x4 Cs[2][2];
#pragma unroll
        for (int mi = 0; mi < 2; ++mi)
#pragma unroll
          for (int nt = 0; nt < 2; ++nt) Cs[mi][nt] = (f32x4){0.f, 0.f, 0.f, 0.f};
#pragma unroll
        for (int mi = 0; mi < 2; ++mi) {
          int mt = mtp * 2 + mi;
          short8 afr = (quad == 0) ? *(const short8*)&sh_rbh[ri][mt * 16 + nlo][0] : zero8;
#pragma unroll
          for (int nt = 0; nt < 2; ++nt)
            Cs[mi][nt] = __builtin_amdgcn_mfma_f32_16x16x32_bf16(afr, bw[nt], Cs[mi][nt], 0, 0, 0);
        }
#pragma unroll
        for (int mi = 0; mi < 2; ++mi)
#pragma unroll
          for (int nt = 0; nt < 2; ++nt)
#pragma unroll
            for (int reg = 0; reg < 4; ++reg) {
              int s = (mtp * 2 + mi) * 16 + quad * 4 + reg;
              int c = w * 32 + nt * 16 + nlo;
              sh_S[ri][s][c] = f2bf(silu_f(Cs[mi][nt][reg]));
            }
      }
  }
  __syncthreads();

  // ---- Main GEMM + epilogue, both receivers; B-frags & hbv shared ----
  const unsigned short* Bbase = Wpack + l * 16384;
  short8 bfr[4][2];
#pragma unroll
  for (int kt = 0; kt < 4; ++kt)
#pragma unroll
    for (int nt = 0; nt < 2; ++nt)
      bfr[kt][nt] = *(const short8*)&Bbase[((kt * 128 + w * 32 + nt * 16 + nlo) * 4 + quad) * 8];

  const float invAvg = 1.0f / 63.0f;
#pragma unroll
  for (int ri = 0; ri < 2; ++ri) {
    float acc0[2] = {0.f, 0.f};
    float a1x[2] = {0.f, 0.f};
    float a1y[2] = {0.f, 0.f};
    float a1z[2] = {0.f, 0.f};
#pragma unroll
    for (int mt = 0; mt < 4; ++mt) {
      short8 afr[4];
      int s_a = mt * 16 + nlo;
#pragma unroll
      for (int kt = 0; kt < 4; ++kt)
        afr[kt] = *(const short8*)&sh_S[ri][s_a][kt * 32 + quad * 8];
      float ux[4], uy[4], uz[4];
#pragma unroll
      for (int reg = 0; reg < 4; ++reg) {
        int s = mt * 16 + quad * 4 + reg;
        ux[reg] = sh_u[ri][0][s]; uy[reg] = sh_u[ri][1][s]; uz[reg] = sh_u[ri][2][s];
      }
#pragma unroll
      for (int nt = 0; nt < 2; ++nt) {
        f32x4 C = {0.f, 0.f, 0.f, 0.f};
#pragma unroll
        for (int kt = 0; kt < 4; ++kt)
          C = __builtin_amdgcn_mfma_f32_16x16x32_bf16(afr[kt], bfr[kt][nt], C, 0, 0, 0);
#pragma unroll
        for (int reg = 0; reg < 4; ++reg) {
          float m0 = C[reg] * hbv[mt][nt][reg];
          acc0[nt] += m0;
          a1x[nt] += m0 * ux[reg];
          a1y[nt] += m0 * uy[reg];
          a1z[nt] += m0 * uz[reg];
        }
      }
    }
#pragma unroll
    for (int nt = 0; nt < 2; ++nt) {
      float q0 = acc0[nt], q1 = a1x[nt], q2 = a1y[nt], q3 = a1z[nt];
      q0 += __shfl_xor(q0, 16); q0 += __shfl_xor(q0, 32);
      q1 += __shfl_xor(q1, 16); q1 += __shfl_xor(q1, 32);
      q2 += __shfl_xor(q2, 16); q2 += __shfl_xor(q2, 32);
      q3 += __shfl_xor(q3, 16); q3 += __shfl_xor(q3, 32);
      if (quad == 0) {
        size_t base = (size_t)(b * NN + r0 + ri) * HH + w * 32 + nt * 16 + nlo;
        ap[base]             = q0 * invAvg;
        ap[PLANE + base]     = q1 * invAvg;
        ap[2 * PLANE + base] = q2 * invAvg;
        ap[3 * PLANE + base] = q3 * invAvg;
      }
    }
  }
}

// Layer-0 node update via MFMA, 16 rows/block (grid 256):
// hout = hin + a0@Wupd0 ; v planes = a1@Wmix0.
__global__ __launch_bounds__(256) void k_update(
    const float* __restrict__ ap, const float* __restrict__ hin,
    float* __restrict__ hout, float* __restrict__ vp,
    const unsigned short* __restrict__ Wpack) {
  __shared__ __align__(16) unsigned short sh_a[4][16][136];
  int tid = threadIdx.x, w = tid >> 6, lane = tid & 63;
  int nlo = lane & 15, quad = lane >> 4;
  int row0 = blockIdx.x * 16;
#pragma unroll
  for (int p = 0; p < 4; ++p)
#pragma unroll
    for (int ii = 0; ii < 4; ++ii) {
      int i = ii * 256 + tid;
      int rr = i >> 6, c2 = (i & 63) * 2;
      f32x2 t = *(const f32x2*)&ap[p * PLANE + (size_t)(row0 + rr) * HH + c2];
      *(unsigned*)&sh_a[p][rr][c2] = (unsigned)f2bf(t.x) | ((unsigned)f2bf(t.y) << 16);
    }
  __syncthreads();
  f32x4 Ch[2] = {{0,0,0,0},{0,0,0,0}}, Cx[2] = {{0,0,0,0},{0,0,0,0}};
  f32x4 Cy[2] = {{0,0,0,0},{0,0,0,0}}, Cz[2] = {{0,0,0,0},{0,0,0,0}};
  gemm16(sh_a[0], Wpack + 2 * 16384, w, nlo, quad, Ch);
  gemm16(sh_a[1], Wpack + 4 * 16384, w, nlo, quad, Cx);
  gemm16(sh_a[2], Wpack + 4 * 16384, w, nlo, quad, Cy);
  gemm16(sh_a[3], Wpack + 4 * 16384, w, nlo, quad, Cz);
#pragma unroll
  for (int nt = 0; nt < 2; ++nt)
#pragma unroll
    for (int reg = 0; reg < 4; ++reg) {
      size_t row = row0 + quad * 4 + reg;
      int col = w * 32 + nt * 16 + nlo;
      hout[row * HH + col] = hin[row * HH + col] + Ch[nt][reg];
      vp[0 * PLANE + row * HH + col] = Cx[nt][reg];
      vp[1 * PLANE + row * HH + col] = Cy[nt][reg];
      vp[2 * PLANE + row * HH + col] = Cz[nt][reg];
    }
}

// Layer-1 update + full readout, 16 rows/block (grid 256):
// h = hin + a0@Wupd1; v = vin + a1@Wmix1; g = silu(h@Wg1)@Wg2;
// out[row,d] = sum_c v[row,c,d]*g[row,c] * fs.
__global__ __launch_bounds__(256) void k_update_ro(
    const float* __restrict__ ap, const float* __restrict__ hin,
    const float* __restrict__ vp,
    const unsigned short* __restrict__ Wpack,
    const float* __restrict__ fs, float* __restrict__ out) {
  __shared__ __align__(16) unsigned short sh_a[4][16][136];   // [0] aliased by q
  __shared__ __align__(16) unsigned short sh_h[16][136];
  __shared__ float red[4][16][3];
  int tid = threadIdx.x, w = tid >> 6, lane = tid & 63;
  int nlo = lane & 15, quad = lane >> 4;
  int row0 = blockIdx.x * 16;
#pragma unroll
  for (int p = 0; p < 4; ++p)
#pragma unroll
    for (int ii = 0; ii < 4; ++ii) {
      int i = ii * 256 + tid;
      int rr = i >> 6, c2 = (i & 63) * 2;
      f32x2 t = *(const f32x2*)&ap[p * PLANE + (size_t)(row0 + rr) * HH + c2];
      *(unsigned*)&sh_a[p][rr][c2] = (unsigned)f2bf(t.x) | ((unsigned)f2bf(t.y) << 16);
    }
  __syncthreads();
  f32x4 Ch[2] = {{0,0,0,0},{0,0,0,0}}, Cx[2] = {{0,0,0,0},{0,0,0,0}};
  f32x4 Cy[2] = {{0,0,0,0},{0,0,0,0}}, Cz[2] = {{0,0,0,0},{0,0,0,0}};
  gemm16(sh_a[0], Wpack + 3 * 16384, w, nlo, quad, Ch);
  gemm16(sh_a[1], Wpack + 5 * 16384, w, nlo, quad, Cx);
  gemm16(sh_a[2], Wpack + 5 * 16384, w, nlo, quad, Cy);
  gemm16(sh_a[3], Wpack + 5 * 16384, w, nlo, quad, Cz);
  // epilogue: h -> bf16 LDS; vin += into Cv regs
#pragma unroll
  for (int nt = 0; nt < 2; ++nt)
#pragma unroll
    for (int reg = 0; reg < 4; ++reg) {
      int rl = quad * 4 + reg;
      size_t row = row0 + rl;
      int col = w * 32 + nt * 16 + nlo;
      sh_h[rl][col] = f2bf(hin[row * HH + col] + Ch[nt][reg]);
      Cx[nt][reg] += vp[0 * PLANE + row * HH + col];
      Cy[nt][reg] += vp[1 * PLANE + row * HH + col];
      Cz[nt][reg] += vp[2 * PLANE + row * HH + col];
    }
  __syncthreads();   // sh_h ready; sh_a reads done -> sh_a[0] free to alias
  unsigned short (*sh_q)[136] = sh_a[0];
  f32x4 Cq[2] = {{0,0,0,0},{0,0,0,0}};
  gemm16(sh_h, Wpack + 6 * 16384, w, nlo, quad, Cq);
#pragma unroll
  for (int nt = 0; nt < 2; ++nt)
#pragma unroll
    for (int reg = 0; reg < 4; ++reg)
      sh_q[quad * 4 + reg][w * 32 + nt * 16 + nlo] = f2bf(silu_f(Cq[nt][reg]));
  __syncthreads();
  f32x4 Cg[2] = {{0,0,0,0},{0,0,0,0}};
  gemm16(sh_q, Wpack + 7 * 16384, w, nlo, quad, Cg);
  // contraction: per-row sums of g*v over this wave's 32 cols
  float pr[3][4];
#pragma unroll
  for (int d = 0; d < 3; ++d)
#pragma unroll
    for (int reg = 0; reg < 4; ++reg) pr[d][reg] = 0.f;
#pragma unroll
  for (int nt = 0; nt < 2; ++nt)
#pragma unroll
    for (int reg = 0; reg < 4; ++reg) {
      float gv = Cg[nt][reg];
      pr[0][reg] += gv * Cx[nt][reg];
      pr[1][reg] += gv * Cy[nt][reg];
      pr[2][reg] += gv * Cz[nt][reg];
    }
#pragma unroll
  for (int off = 1; off < 16; off <<= 1)
#pragma unroll
    for (int d = 0; d < 3; ++d)
#pragma unroll
      for (int reg = 0; reg < 4; ++reg)
        pr[d][reg] += __shfl_xor(pr[d][reg], off);
  if (nlo == 0) {
#pragma unroll
    for (int d = 0; d < 3; ++d)
#pragma unroll
      for (int reg = 0; reg < 4; ++reg)
        red[w][quad * 4 + reg][d] = pr[d][reg];
  }
  __syncthreads();
  if (tid < 48) {
    int row = tid / 3, d = tid % 3;
    float s = red[0][row][d] + red[1][row][d] + red[2][row][d] + red[3][row][d];
    out[(size_t)(row0 + row) * 3 + d] = s * fs[0];
  }
}

extern "C" void kernel_launch(void* const* d_in, const int* in_sizes, int n_in,
                              void* d_out, int out_size, void* d_ws, size_t ws_size,
                              hipStream_t stream) {
  const float* pos  = (const float*)d_in[0];
  const int*   z    = (const int*)d_in[1];
  const float* gf   = (const float*)d_in[2];
  const float* emb  = (const float*)d_in[3];
  const float* Wt   = (const float*)d_in[4];
  const float* Wr1  = (const float*)d_in[5];
  const float* Wr2  = (const float*)d_in[6];
  const float* Wupd = (const float*)d_in[7];
  const float* Wmix = (const float*)d_in[8];
  const float* Wg1  = (const float*)d_in[9];
  const float* Wg2  = (const float*)d_in[10];
  const float* fs   = (const float*)d_in[11];
  float* out = (float*)d_out;

  float* ws = (float*)d_ws;
  float* hA = ws;                            // 2 MB
  float* hB = ws + PLANE;                    // 2 MB
  float* vp = ws + 2 * PLANE;                // 6 MB (3 planes)
  float* apl = ws + 5 * PLANE;               // 8 MB (4 planes)
  unsigned short* Wpack = (unsigned short*)(ws + 9 * PLANE);  // 272 KB

  k_init<<<dim3(BB), dim3(256), 0, stream>>>(emb, z, gf, Wt, Wr1, Wr2, Wupd,
                                             Wmix, Wg1, Wg2, hA, Wpack);
  k_layer<<<dim3(BB * 32), dim3(256), 0, stream>>>(pos, hA, apl, Wpack, 0);
  k_update<<<dim3(256), dim3(256), 0, stream>>>(apl, hA, hB, vp, Wpack);
  k_layer<<<dim3(BB * 32), dim3(256), 0, stream>>>(pos, hB, apl, Wpack, 1);
  k_update_ro<<<dim3(256), dim3(256), 0, stream>>>(apl, hB, vp, Wpack, fs, out);
}